// Round 7
// baseline (94.264 us; speedup 1.0000x reference)
//
#include <hip/hip_runtime.h>
#include <math.h>

// Problem constants: N=8, S=8192, C=1, K=1024, V=64
#define NS   65536
#define KK   1024
#define VV   64
#define SPB  64               // samples per block (4 m-tiles of 16)
#define NB   (NS / SPB)       // 1024 blocks -> up to 4 blocks/CU = 32 waves/CU
#define NW   8                // waves per block (512 threads)
#define TPW  2                // code tiles per wave per pass (32 codes)
#define NPASS 4               // 8 waves x 2 tiles x 4 passes = 64 tiles = 1024 codes
#define NMT  (SPB / 16)       // 4 sample-tiles per block

// Output layout (flat, return order):
#define OUT0_OFF 0            // (8,8192,1,64) = 4,194,304
#define OUT1_OFF 4194304
#define OUT2_OFF 4259840
#define ENT_OFF  4325376      // entropy scalar

// ws layout: [0,4K) hist u32; [4K,8K) cinit f32 (=1-0.5|e|^2); [8K,136K) frag-linear bf16 codebook

typedef __attribute__((ext_vector_type(8))) short bf16x8;
typedef __attribute__((ext_vector_type(4))) float f32x4;

__device__ __forceinline__ short f2bf(float f) {
    unsigned u = __float_as_uint(f);
    u = (u + 0x7fffu + ((u >> 16) & 1u)) >> 16;   // RNE
    return (short)u;
}

// prep (wide): 8192 threads, one (code, granule) each. FRAG-LINEAR bf16 codebook:
// tile T (codes 16T..16T+15), frag f: 1KB region where lane l = quad*16+col holds
// code (16T+col), granule (4f+quad), 16B. |e|^2 reduced over the 8 granule-lanes.
__global__ void vq_prep(const float* __restrict__ emb, unsigned int* __restrict__ hist,
                        float* __restrict__ cinit, short* __restrict__ cb) {
    const int t = blockIdx.x * blockDim.x + threadIdx.x;   // 0..8191
    const int c = t >> 3;          // code
    const int g = t & 7;           // granule (8 floats)
    if (t < KK) hist[t] = 0u;
    const float* ep = emb + (size_t)c * VV + g * 8;
    float4 f0 = *(const float4*)(ep);
    float4 f1 = *(const float4*)(ep + 4);
    float s = 0.f;
    s=fmaf(f0.x,f0.x,s); s=fmaf(f0.y,f0.y,s); s=fmaf(f0.z,f0.z,s); s=fmaf(f0.w,f0.w,s);
    s=fmaf(f1.x,f1.x,s); s=fmaf(f1.y,f1.y,s); s=fmaf(f1.z,f1.z,s); s=fmaf(f1.w,f1.w,s);
    union { short sh[8]; bf16x8 v; } pk;
    pk.sh[0]=f2bf(f0.x); pk.sh[1]=f2bf(f0.y); pk.sh[2]=f2bf(f0.z); pk.sh[3]=f2bf(f0.w);
    pk.sh[4]=f2bf(f1.x); pk.sh[5]=f2bf(f1.y); pk.sh[6]=f2bf(f1.z); pk.sh[7]=f2bf(f1.w);
    const int T = c >> 4, cc = c & 15;
    short* dst = cb + (size_t)T * 1024 + (g >> 2) * 512 + ((g & 3) * 16 + cc) * 8;
    *(bf16x8*)dst = pk.v;
    // |e|^2 over the 8 consecutive lanes owning this code
    s += __shfl_xor(s, 1, 64);
    s += __shfl_xor(s, 2, 64);
    s += __shfl_xor(s, 4, 64);
    if (g == 0) cinit[c] = 1.0f - 0.5f * s;   // MFMA C-init; scores in (0.85,1.15)
}

// launch_bounds (512,4): spill-proof. TPW=2 trims live regs so allocator can
// land <=64 -> 4 blocks/CU (32 waves/CU). NO cross-block coupling: block ends
// at its out0 stores + hist atomics (entropy moved to vq_ent; kernel-boundary
// release/acquire provides hist coherence -- no counter, no tail barriers).
__global__ __launch_bounds__(512, 4) void vq_main(
    const float* __restrict__ x, const float* __restrict__ emb,
    const float* __restrict__ cinit, const short* __restrict__ cb,
    unsigned int* __restrict__ hist,
    float* __restrict__ out0, float* __restrict__ out1, float* __restrict__ out2)
{
    __shared__ __align__(16) char  sA[SPB * 128];     // 8 KB swizzled bf16 samples
    __shared__ float    sXn[SPB];
    __shared__ unsigned sRed[SPB][NW + 1];            // +1 pad -> <=2-way banks (free)
    __shared__ unsigned sPkF[SPB];

    const int tid  = threadIdx.x;
    const int lane = tid & 63;
    const int wv   = tid >> 6;        // 0..7
    const int col  = lane & 15;       // B-operand n index (sample-within-tile)
    const int quad = lane >> 4;       // k-granule group
    const int samp0 = blockIdx.x * SPB;

    // ---- stage x -> sA (bf16, XOR-swizzled granules) + fp32 |x|^2 ----
    // thread t: sample s = t>>3, granule g = t&7 -> 8 consecutive floats (32B, coalesced)
    {
        const int s = tid >> 3, g = tid & 7;
        const float* xp = x + (size_t)(samp0 + s) * VV + g * 8;
        float4 f0 = *(const float4*)(xp);
        float4 f1 = *(const float4*)(xp + 4);
        float sm = 0.f;
        sm=fmaf(f0.x,f0.x,sm); sm=fmaf(f0.y,f0.y,sm); sm=fmaf(f0.z,f0.z,sm); sm=fmaf(f0.w,f0.w,sm);
        sm=fmaf(f1.x,f1.x,sm); sm=fmaf(f1.y,f1.y,sm); sm=fmaf(f1.z,f1.z,sm); sm=fmaf(f1.w,f1.w,sm);
        union { short sh[8]; bf16x8 v; } pa;
        pa.sh[0]=f2bf(f0.x); pa.sh[1]=f2bf(f0.y); pa.sh[2]=f2bf(f0.z); pa.sh[3]=f2bf(f0.w);
        pa.sh[4]=f2bf(f1.x); pa.sh[5]=f2bf(f1.y); pa.sh[6]=f2bf(f1.z); pa.sh[7]=f2bf(f1.w);
        short* base = (short*)(sA + s * 128);
        // granule g at swizzled slot g ^ (s&7): matches read swizzle below
        *(bf16x8*)(base + ((g ^ (s & 7)) << 3)) = pa.v;
        // reduce |x|^2 over the 8 granules (8 consecutive lanes own one sample)
        sm += __shfl_xor(sm, 1, 64);
        sm += __shfl_xor(sm, 2, 64);
        sm += __shfl_xor(sm, 4, 64);
        if ((tid & 7) == 0) sXn[s] = sm;
    }

    // B-frag read offsets (verified conflict-free pattern: row*128 ^ granule swizzle)
    const int rb0 = col * 128 + (( quad      ^ (col & 7)) << 4);
    const int rb1 = col * 128 + (((4 + quad) ^ (col & 7)) << 4);

    // packed running maxima per m-tile: high 22 bits = score, low 10 = 1023-code
    unsigned pmv[NMT];
    #pragma unroll
    for (int j = 0; j < NMT; ++j) pmv[j] = 0u;

    for (int p = 0; p < NPASS; ++p) {
        // ---- this wave's 32 codes -> registers (A-frags, cinit, base tags) ----
        bf16x8   af0[TPW], af1[TPW];
        f32x4    cv[TPW];
        unsigned tg[TPW];
        const int Tb = p * 16 + wv * TPW;
        #pragma unroll
        for (int t = 0; t < TPW; ++t) {
            const char* cp = (const char*)cb + (size_t)(Tb + t) * 2048;
            af0[t] = *(const bf16x8*)(cp + lane * 16);          // k 0..31, fully coalesced
            af1[t] = *(const bf16x8*)(cp + 1024 + lane * 16);   // k 32..63
            cv[t]  = *(const f32x4*)(cinit + (Tb + t) * 16 + quad * 4);
            tg[t]  = 1023u - (unsigned)((Tb + t) * 16 + quad * 4);
        }
        if (p == 0) __syncthreads();   // sA/sXn ready; pass-0 frag loads overlapped staging

        // ---- barrier-free main loop: 4 sample tiles x 2 code tiles ----
        #pragma unroll
        for (int mt = 0; mt < NMT; ++mt) {
            const char* Bp = sA + mt * 2048;
            bf16x8 b0 = *(const bf16x8*)(Bp + rb0);
            bf16x8 b1 = *(const bf16x8*)(Bp + rb1);
            #pragma unroll
            for (int t = 0; t < TPW; ++t) {
                f32x4 acc = __builtin_amdgcn_mfma_f32_16x16x32_bf16(af0[t], b0, cv[t], 0, 0, 0);
                acc       = __builtin_amdgcn_mfma_f32_16x16x32_bf16(af1[t], b1, acc,   0, 0, 0);
                // D: row = code (quad*4+r), col = sample. Pack score|invcode.
                // (bits|tg)-r == bits|(tg-r): tg>=3>=r, no borrow past bit 9.
                unsigned u0 = ((__float_as_uint(acc[0]) & 0xFFFFFC00u) | tg[t]);
                unsigned u1 = ((__float_as_uint(acc[1]) & 0xFFFFFC00u) | tg[t]) - 1u;
                unsigned u2 = ((__float_as_uint(acc[2]) & 0xFFFFFC00u) | tg[t]) - 2u;
                unsigned u3 = ((__float_as_uint(acc[3]) & 0xFFFFFC00u) | tg[t]) - 3u;
                unsigned m0 = u0 > u1 ? u0 : u1;
                unsigned m1 = u2 > u3 ? u2 : u3;
                unsigned mm = m0 > m1 ? m0 : m1;
                pmv[mt] = pmv[mt] > mm ? pmv[mt] : mm;
            }
        }
    }

    // ---- per-sample max over the quad dim (codes quad*4+r live in quad groups) ----
    #pragma unroll
    for (int j = 0; j < NMT; ++j) {
        unsigned o;
        o = (unsigned)__shfl_xor((int)pmv[j], 16, 64); pmv[j] = o > pmv[j] ? o : pmv[j];
        o = (unsigned)__shfl_xor((int)pmv[j], 32, 64); pmv[j] = o > pmv[j] ? o : pmv[j];
    }
    // each quad writes sample quad*16+col (static-index select of pmv[quad])
    {
        unsigned w0 = (quad & 1) ? pmv[1] : pmv[0];
        unsigned w1 = (quad & 1) ? pmv[3] : pmv[2];
        unsigned lo = (quad & 2) ? w1 : w0;            // pmv[quad]
        sRed[quad * 16 + col][wv] = lo;
    }
    __syncthreads();

    // ---- final per-sample reduce over 8 waves + out1/out2/hist ----
    if (tid < SPB) {
        unsigned pbest = sRed[tid][0];
        #pragma unroll
        for (int w = 1; w < NW; ++w) {
            unsigned o = sRed[tid][w];
            pbest = o > pbest ? o : pbest;
        }
        sPkF[tid] = pbest;
        int   code = 1023 - (int)(pbest & 1023u);
        float sf   = __uint_as_float(pbest & 0xFFFFFC00u);
        float d    = fmaf(-2.f, sf - 1.0f, sXn[tid]);   // sf-1 exact (Sterbenz)
        int n = samp0 + tid;
        out1[n] = d;
        out2[n] = d;
        atomicAdd(&hist[code], 1u);   // device-scope; visible to vq_ent via kernel boundary
    }
    __syncthreads();

    // ---- out0 gather: lane-contiguous float4 stores (1KB/wave/instr); block ends here ----
    {
        float4* dstB = (float4*)(out0 + (size_t)samp0 * VV);   // 1024 float4s per block
        #pragma unroll
        for (int i = 0; i < 2; ++i) {
            const int idx  = i * 512 + tid;
            const int smp  = idx >> 4;
            const int part = idx & 15;
            const int code = 1023 - (int)(sPkF[smp] & 1023u);
            dstB[idx] = *((const float4*)(emb + (size_t)code * VV) + part);
        }
    }
}

// entropy: separate 1-block kernel. Kernel-boundary release/acquire makes all
// hist atomics visible to PLAIN loads here -- no RMW reads, no completion counter.
__global__ void vq_ent(const unsigned int* __restrict__ hist, float* __restrict__ entOut) {
    __shared__ float sPart[16];
    const int tid  = threadIdx.x;      // 1024 threads, 16 waves
    const int lane = tid & 63;
    const int wv   = tid >> 6;
    unsigned c = hist[tid];
    float e = 0.f;
    if (c) { float pr = (float)c * (1.0f / (float)NS); e = -pr * logf(pr); }
    #pragma unroll
    for (int off = 32; off > 0; off >>= 1) e += __shfl_down(e, off, 64);
    if (lane == 0) sPart[wv] = e;
    __syncthreads();
    if (tid == 0) {
        float s = 0.f;
        #pragma unroll
        for (int i = 0; i < 16; ++i) s += sPart[i];
        entOut[0] = s;
    }
}

extern "C" void kernel_launch(void* const* d_in, const int* in_sizes, int n_in,
                              void* d_out, int out_size, void* d_ws, size_t ws_size,
                              hipStream_t stream) {
    const float* x   = (const float*)d_in[0];   // (8,8192,1,64) fp32
    const float* emb = (const float*)d_in[1];   // (1,1024,64) fp32
    float* out = (float*)d_out;
    unsigned int* hist  = (unsigned int*)d_ws;
    float*        cinit = (float*)((char*)d_ws + 4096);
    short*        cb    = (short*)((char*)d_ws + 8192);   // frag-linear bf16 codebook, 128 KB

    vq_prep<<<32, 256, 0, stream>>>(emb, hist, cinit, cb);
    vq_main<<<NB, 512, 0, stream>>>(x, emb, cinit, cb, hist,
                                    out + OUT0_OFF, out + OUT1_OFF, out + OUT2_OFF);
    vq_ent<<<1, 1024, 0, stream>>>(hist, out + ENT_OFF);
}

// Round 8
// 92.427 us; speedup vs baseline: 1.0199x; 1.0199x over previous
//
#include <hip/hip_runtime.h>
#include <math.h>

// Problem constants: N=8, S=8192, C=1, K=1024, V=64
#define NS   65536
#define KK   1024
#define VV   64
#define SPB  64               // samples per block (4 m-tiles of 16)
#define NB   (NS / SPB)       // 1024 blocks
#define NW   8                // waves per block (512 threads)
#define TPW  2                // code tiles per wave per pass (32 codes)
#define NPASS 4               // 8 waves x 2 tiles x 4 passes = 64 tiles = 1024 codes
#define NMT  (SPB / 16)       // 4 sample-tiles per block

// Output layout (flat, return order):
#define OUT0_OFF 0            // (8,8192,1,64) = 4,194,304
#define OUT1_OFF 4194304
#define OUT2_OFF 4259840
#define ENT_OFF  4325376      // entropy scalar

// ws layout: [0,4K) hist u32; [4K,8K) cinit f32 (=1-0.5|e|^2); [8K,136K) frag-linear bf16 codebook

typedef __attribute__((ext_vector_type(8))) short bf16x8;
typedef __attribute__((ext_vector_type(4))) float f32x4;

__device__ __forceinline__ short f2bf(float f) {
    unsigned u = __float_as_uint(f);
    u = (u + 0x7fffu + ((u >> 16) & 1u)) >> 16;   // RNE
    return (short)u;
}

// prep (wide): 8192 threads, one (code, granule) each. FRAG-LINEAR bf16 codebook:
// tile T (codes 16T..16T+15), frag f: 1KB region where lane l = quad*16+col holds
// code (16T+col), granule (4f+quad), 16B. |e|^2 reduced over the 8 granule-lanes.
__global__ void vq_prep(const float* __restrict__ emb, unsigned int* __restrict__ hist,
                        float* __restrict__ cinit, short* __restrict__ cb) {
    const int t = blockIdx.x * blockDim.x + threadIdx.x;   // 0..8191
    const int c = t >> 3;          // code
    const int g = t & 7;           // granule (8 floats)
    if (t < KK) hist[t] = 0u;
    const float* ep = emb + (size_t)c * VV + g * 8;
    float4 f0 = *(const float4*)(ep);
    float4 f1 = *(const float4*)(ep + 4);
    float s = 0.f;
    s=fmaf(f0.x,f0.x,s); s=fmaf(f0.y,f0.y,s); s=fmaf(f0.z,f0.z,s); s=fmaf(f0.w,f0.w,s);
    s=fmaf(f1.x,f1.x,s); s=fmaf(f1.y,f1.y,s); s=fmaf(f1.z,f1.z,s); s=fmaf(f1.w,f1.w,s);
    union { short sh[8]; bf16x8 v; } pk;
    pk.sh[0]=f2bf(f0.x); pk.sh[1]=f2bf(f0.y); pk.sh[2]=f2bf(f0.z); pk.sh[3]=f2bf(f0.w);
    pk.sh[4]=f2bf(f1.x); pk.sh[5]=f2bf(f1.y); pk.sh[6]=f2bf(f1.z); pk.sh[7]=f2bf(f1.w);
    const int T = c >> 4, cc = c & 15;
    short* dst = cb + (size_t)T * 1024 + (g >> 2) * 512 + ((g & 3) * 16 + cc) * 8;
    *(bf16x8*)dst = pk.v;
    // |e|^2 over the 8 consecutive lanes owning this code
    s += __shfl_xor(s, 1, 64);
    s += __shfl_xor(s, 2, 64);
    s += __shfl_xor(s, 4, 64);
    if (g == 0) cinit[c] = 1.0f - 0.5f * s;   // MFMA C-init; scores in (0.85,1.15)
}

// Software-pipelined pass loop: pass p+1's A-frag/cinit loads are ISSUED before
// pass p's compute, double-buffered in registers (static idx via full unroll).
// ~95 VGPR live -> no spill under (512,4); L2 latency hides under MFMA/VALU.
__global__ __launch_bounds__(512, 4) void vq_main(
    const float* __restrict__ x, const float* __restrict__ emb,
    const float* __restrict__ cinit, const short* __restrict__ cb,
    unsigned int* __restrict__ hist,
    float* __restrict__ out0, float* __restrict__ out1, float* __restrict__ out2)
{
    __shared__ __align__(16) char  sA[SPB * 128];     // 8 KB swizzled bf16 samples
    __shared__ float    sXn[SPB];
    __shared__ unsigned sRed[SPB][NW + 1];            // +1 pad -> <=2-way banks (free)
    __shared__ unsigned sPkF[SPB];

    const int tid  = threadIdx.x;
    const int lane = tid & 63;
    const int wv   = tid >> 6;        // 0..7
    const int col  = lane & 15;       // B-operand n index (sample-within-tile)
    const int quad = lane >> 4;       // k-granule group
    const int samp0 = blockIdx.x * SPB;

    // ---- stage x -> sA (bf16, XOR-swizzled granules) + fp32 |x|^2 ----
    // thread t: sample s = t>>3, granule g = t&7 -> 8 consecutive floats (32B, coalesced)
    {
        const int s = tid >> 3, g = tid & 7;
        const float* xp = x + (size_t)(samp0 + s) * VV + g * 8;
        float4 f0 = *(const float4*)(xp);
        float4 f1 = *(const float4*)(xp + 4);
        float sm = 0.f;
        sm=fmaf(f0.x,f0.x,sm); sm=fmaf(f0.y,f0.y,sm); sm=fmaf(f0.z,f0.z,sm); sm=fmaf(f0.w,f0.w,sm);
        sm=fmaf(f1.x,f1.x,sm); sm=fmaf(f1.y,f1.y,sm); sm=fmaf(f1.z,f1.z,sm); sm=fmaf(f1.w,f1.w,sm);
        union { short sh[8]; bf16x8 v; } pa;
        pa.sh[0]=f2bf(f0.x); pa.sh[1]=f2bf(f0.y); pa.sh[2]=f2bf(f0.z); pa.sh[3]=f2bf(f0.w);
        pa.sh[4]=f2bf(f1.x); pa.sh[5]=f2bf(f1.y); pa.sh[6]=f2bf(f1.z); pa.sh[7]=f2bf(f1.w);
        short* base = (short*)(sA + s * 128);
        // granule g at swizzled slot g ^ (s&7): matches read swizzle below
        *(bf16x8*)(base + ((g ^ (s & 7)) << 3)) = pa.v;
        // reduce |x|^2 over the 8 granules (8 consecutive lanes own one sample)
        sm += __shfl_xor(sm, 1, 64);
        sm += __shfl_xor(sm, 2, 64);
        sm += __shfl_xor(sm, 4, 64);
        if ((tid & 7) == 0) sXn[s] = sm;
    }

    // B-frag read offsets (verified conflict-free pattern: row*128 ^ granule swizzle)
    const int rb0 = col * 128 + (( quad      ^ (col & 7)) << 4);
    const int rb1 = col * 128 + (((4 + quad) ^ (col & 7)) << 4);

    // packed running maxima per m-tile: high 22 bits = score, low 10 = 1023-code
    unsigned pmv[NMT];
    #pragma unroll
    for (int j = 0; j < NMT; ++j) pmv[j] = 0u;

    // ---- double-buffered A-frag/cinit registers; pass-0 loads overlap staging ----
    bf16x8 af0[2][TPW], af1[2][TPW];
    f32x4  cv[2][TPW];
    #pragma unroll
    for (int t = 0; t < TPW; ++t) {
        const char* cp = (const char*)cb + (size_t)(wv * TPW + t) * 2048;
        af0[0][t] = *(const bf16x8*)(cp + lane * 16);          // k 0..31, coalesced
        af1[0][t] = *(const bf16x8*)(cp + 1024 + lane * 16);   // k 32..63
        cv[0][t]  = *(const f32x4*)(cinit + (wv * TPW + t) * 16 + quad * 4);
    }
    __syncthreads();   // sA/sXn ready (pass-0 frag loads issued above the barrier)

    #pragma unroll
    for (int p = 0; p < NPASS; ++p) {
        const int cur = p & 1, nxt = cur ^ 1;      // constant after unroll (rule #20 safe)
        // ---- prefetch pass p+1 (issued BEFORE compute; lands during MFMA work) ----
        if (p + 1 < NPASS) {
            const int Tn = (p + 1) * 16 + wv * TPW;
            #pragma unroll
            for (int t = 0; t < TPW; ++t) {
                const char* cp = (const char*)cb + (size_t)(Tn + t) * 2048;
                af0[nxt][t] = *(const bf16x8*)(cp + lane * 16);
                af1[nxt][t] = *(const bf16x8*)(cp + 1024 + lane * 16);
                cv[nxt][t]  = *(const f32x4*)(cinit + (Tn + t) * 16 + quad * 4);
            }
        }
        const int Tb = p * 16 + wv * TPW;

        // ---- barrier-free compute: 4 sample tiles x 2 code tiles ----
        #pragma unroll
        for (int mt = 0; mt < NMT; ++mt) {
            const char* Bp = sA + mt * 2048;
            bf16x8 b0 = *(const bf16x8*)(Bp + rb0);
            bf16x8 b1 = *(const bf16x8*)(Bp + rb1);
            #pragma unroll
            for (int t = 0; t < TPW; ++t) {
                f32x4 acc = __builtin_amdgcn_mfma_f32_16x16x32_bf16(af0[cur][t], b0, cv[cur][t], 0, 0, 0);
                acc       = __builtin_amdgcn_mfma_f32_16x16x32_bf16(af1[cur][t], b1, acc,        0, 0, 0);
                // D: row = code (quad*4+r), col = sample. Pack score|invcode.
                // (bits|tg)-r == bits|(tg-r): tg>=3>=r, no borrow past bit 9.
                const unsigned tg = 1023u - (unsigned)((Tb + t) * 16 + quad * 4);
                unsigned u0 = ((__float_as_uint(acc[0]) & 0xFFFFFC00u) | tg);
                unsigned u1 = ((__float_as_uint(acc[1]) & 0xFFFFFC00u) | tg) - 1u;
                unsigned u2 = ((__float_as_uint(acc[2]) & 0xFFFFFC00u) | tg) - 2u;
                unsigned u3 = ((__float_as_uint(acc[3]) & 0xFFFFFC00u) | tg) - 3u;
                unsigned m0 = u0 > u1 ? u0 : u1;
                unsigned m1 = u2 > u3 ? u2 : u3;
                unsigned mm = m0 > m1 ? m0 : m1;
                pmv[mt] = pmv[mt] > mm ? pmv[mt] : mm;
            }
        }
    }

    // ---- per-sample max over the quad dim (codes quad*4+r live in quad groups) ----
    #pragma unroll
    for (int j = 0; j < NMT; ++j) {
        unsigned o;
        o = (unsigned)__shfl_xor((int)pmv[j], 16, 64); pmv[j] = o > pmv[j] ? o : pmv[j];
        o = (unsigned)__shfl_xor((int)pmv[j], 32, 64); pmv[j] = o > pmv[j] ? o : pmv[j];
    }
    // each quad writes sample quad*16+col (static-index select of pmv[quad])
    {
        unsigned w0 = (quad & 1) ? pmv[1] : pmv[0];
        unsigned w1 = (quad & 1) ? pmv[3] : pmv[2];
        unsigned lo = (quad & 2) ? w1 : w0;            // pmv[quad]
        sRed[quad * 16 + col][wv] = lo;
    }
    __syncthreads();

    // ---- final per-sample reduce over 8 waves + out1/out2/hist ----
    if (tid < SPB) {
        unsigned pbest = sRed[tid][0];
        #pragma unroll
        for (int w = 1; w < NW; ++w) {
            unsigned o = sRed[tid][w];
            pbest = o > pbest ? o : pbest;
        }
        sPkF[tid] = pbest;
        int   code = 1023 - (int)(pbest & 1023u);
        float sf   = __uint_as_float(pbest & 0xFFFFFC00u);
        float d    = fmaf(-2.f, sf - 1.0f, sXn[tid]);   // sf-1 exact (Sterbenz)
        int n = samp0 + tid;
        out1[n] = d;
        out2[n] = d;
        atomicAdd(&hist[code], 1u);   // device-scope; visible to vq_ent via kernel boundary
    }
    __syncthreads();

    // ---- out0 gather: lane-contiguous float4 stores (1KB/wave/instr); block ends here ----
    {
        float4* dstB = (float4*)(out0 + (size_t)samp0 * VV);   // 1024 float4s per block
        #pragma unroll
        for (int i = 0; i < 2; ++i) {
            const int idx  = i * 512 + tid;
            const int smp  = idx >> 4;
            const int part = idx & 15;
            const int code = 1023 - (int)(sPkF[smp] & 1023u);
            dstB[idx] = *((const float4*)(emb + (size_t)code * VV) + part);
        }
    }
}

// entropy: separate 1-block kernel. Kernel-boundary release/acquire makes all
// hist atomics visible to PLAIN loads here -- no RMW reads, no completion counter.
__global__ void vq_ent(const unsigned int* __restrict__ hist, float* __restrict__ entOut) {
    __shared__ float sPart[16];
    const int tid  = threadIdx.x;      // 1024 threads, 16 waves
    const int lane = tid & 63;
    const int wv   = tid >> 6;
    unsigned c = hist[tid];
    float e = 0.f;
    if (c) { float pr = (float)c * (1.0f / (float)NS); e = -pr * logf(pr); }
    #pragma unroll
    for (int off = 32; off > 0; off >>= 1) e += __shfl_down(e, off, 64);
    if (lane == 0) sPart[wv] = e;
    __syncthreads();
    if (tid == 0) {
        float s = 0.f;
        #pragma unroll
        for (int i = 0; i < 16; ++i) s += sPart[i];
        entOut[0] = s;
    }
}

extern "C" void kernel_launch(void* const* d_in, const int* in_sizes, int n_in,
                              void* d_out, int out_size, void* d_ws, size_t ws_size,
                              hipStream_t stream) {
    const float* x   = (const float*)d_in[0];   // (8,8192,1,64) fp32
    const float* emb = (const float*)d_in[1];   // (1,1024,64) fp32
    float* out = (float*)d_out;
    unsigned int* hist  = (unsigned int*)d_ws;
    float*        cinit = (float*)((char*)d_ws + 4096);
    short*        cb    = (short*)((char*)d_ws + 8192);   // frag-linear bf16 codebook, 128 KB

    vq_prep<<<32, 256, 0, stream>>>(emb, hist, cinit, cb);
    vq_main<<<NB, 512, 0, stream>>>(x, emb, cinit, cb, hist,
                                    out + OUT0_OFF, out + OUT1_OFF, out + OUT2_OFF);
    vq_ent<<<1, 1024, 0, stream>>>(hist, out + ENT_OFF);
}